// Round 8
// baseline (866.662 us; speedup 1.0000x reference)
//
#include <hip/hip_runtime.h>
#include <math.h>

// ---------------------------------------------------------------------------
// StageA GNN: wtrans -> encoder -> CSR build -> L x (gateproj, gate, agg) -> head
// R8: transpose all GEMV weights to feature-major (w1t/w2t/gw1t/uw1t/uw2t) so
// each lane loads float4 weight chunks (4x fewer loads per FMA); enc K-loop
// unroll 4 (more loads in flight); agg gather 16-deep batches.
// All fp32 paths bit-identical to R7 -- only load schedule changes.
// ---------------------------------------------------------------------------

typedef unsigned short ushort_t;

__device__ __forceinline__ float bf2f(ushort_t u) {
    return __uint_as_float(((unsigned int)u) << 16);
}
__device__ __forceinline__ ushort_t f2bf(float f) {
    unsigned int x = __float_as_uint(f);
    unsigned int lsb = (x >> 16) & 1u;
    x += 0x7fffu + lsb;                 // round-to-nearest-even
    return (ushort_t)(x >> 16);
}

__device__ __forceinline__ float wave_sum64(float v) {
    #pragma unroll
    for (int o = 32; o > 0; o >>= 1) v += __shfl_xor(v, o, 64);
    return v;
}

// one-time weight transposes to feature-major rows (per-lane contiguous)
__global__ __launch_bounds__(256) void wtrans_kernel(
    const float* __restrict__ w1, const float* __restrict__ w2,
    const float* __restrict__ gw1, const float* __restrict__ uw1,
    const float* __restrict__ uw2,
    float* __restrict__ w1t, float* __restrict__ w2t,
    float* __restrict__ gw1t, float* __restrict__ uw1t,
    float* __restrict__ uw2t) {
    int t = blockIdx.x * blockDim.x + threadIdx.x;
    if (t < 64 * 256) {                      // w1t[n][k] = w1[k][n]
        int n = t >> 8, k = t & 255;
        w1t[t] = w1[(size_t)k * 64 + n];
    }
    if (t < 64 * 64) {                       // w2t[n][k] = w2[k][n]
        int n = t >> 6, k = t & 63;
        w2t[t] = w2[(size_t)k * 64 + n];
    }
    if (t < 64 * 128) {                      // gw1t[n][k] = gw1[k][n], k<128
        int n = t >> 7, k = t & 127;
        gw1t[t] = gw1[(size_t)k * 64 + n];
    }
    if (t < 2 * 64 * 64) {                   // uw1t/uw2t[l][n][k]
        int l = t >> 12, r = t & 4095;
        int n = r >> 6, k = r & 63;
        uw1t[t] = uw1[(size_t)l * 4096 + (size_t)k * 64 + n];
        uw2t[t] = uw2[(size_t)l * 4096 + (size_t)k * 64 + n];
    }
}

// h = relu(relu(x@W1+b1)@W2+b2); 4 rows/wave, transposed weights, unroll 4.
__global__ __launch_bounds__(256) void enc_kernel(
    const float* __restrict__ x, const float* __restrict__ w1t,
    const float* __restrict__ b1, const float* __restrict__ w2t,
    const float* __restrict__ b2,
    float* __restrict__ h, ushort_t* __restrict__ hb, int N, int C) {
    const int lane = threadIdx.x & 63;
    const int wid  = blockIdx.x * (blockDim.x >> 6) + (threadIdx.x >> 6);
    const int nw   = gridDim.x * (blockDim.x >> 6);
    const float b1l = b1[lane], b2l = b2[lane];
    const float* wr1 = w1t + (size_t)lane * C;    // contiguous K row
    const float* wr2 = w2t + (size_t)lane * 64;
    const int nquad = (N + 3) >> 2;
    for (int q = wid; q < nquad; q += nw) {
        const int r0 = q * 4;
        if (r0 + 3 < N) {
            const float* xr = x + (size_t)r0 * C;
            float s0 = 0.f, s1 = 0.f, s2 = 0.f, s3 = 0.f;
            #pragma unroll 4
            for (int k4 = 0; k4 < C / 4; ++k4) {
                float4 wv = *(const float4*)(wr1 + k4 * 4);
                float4 v0 = *(const float4*)(xr + k4 * 4);
                float4 v1 = *(const float4*)(xr + (size_t)C + k4 * 4);
                float4 v2 = *(const float4*)(xr + (size_t)2 * C + k4 * 4);
                float4 v3 = *(const float4*)(xr + (size_t)3 * C + k4 * 4);
                s0 = fmaf(wv.x, v0.x, s0); s0 = fmaf(wv.y, v0.y, s0);
                s0 = fmaf(wv.z, v0.z, s0); s0 = fmaf(wv.w, v0.w, s0);
                s1 = fmaf(wv.x, v1.x, s1); s1 = fmaf(wv.y, v1.y, s1);
                s1 = fmaf(wv.z, v1.z, s1); s1 = fmaf(wv.w, v1.w, s1);
                s2 = fmaf(wv.x, v2.x, s2); s2 = fmaf(wv.y, v2.y, s2);
                s2 = fmaf(wv.z, v2.z, s2); s2 = fmaf(wv.w, v2.w, s2);
                s3 = fmaf(wv.x, v3.x, s3); s3 = fmaf(wv.y, v3.y, s3);
                s3 = fmaf(wv.z, v3.z, s3); s3 = fmaf(wv.w, v3.w, s3);
            }
            float t0 = fmaxf(s0 + b1l, 0.f), t1 = fmaxf(s1 + b1l, 0.f);
            float t2 = fmaxf(s2 + b1l, 0.f), t3 = fmaxf(s3 + b1l, 0.f);
            float c0 = 0.f, c1 = 0.f, c2 = 0.f, c3 = 0.f;
            #pragma unroll
            for (int k4 = 0; k4 < 16; ++k4) {
                float4 wv = *(const float4*)(wr2 + k4 * 4);
                #define G2(J, COMP) { \
                    c0 = fmaf(wv.COMP, __shfl(t0, k4 * 4 + J, 64), c0); \
                    c1 = fmaf(wv.COMP, __shfl(t1, k4 * 4 + J, 64), c1); \
                    c2 = fmaf(wv.COMP, __shfl(t2, k4 * 4 + J, 64), c2); \
                    c3 = fmaf(wv.COMP, __shfl(t3, k4 * 4 + J, 64), c3); }
                G2(0, x) G2(1, y) G2(2, z) G2(3, w)
                #undef G2
            }
            float h0 = fmaxf(c0 + b2l, 0.f), h1 = fmaxf(c1 + b2l, 0.f);
            float h2 = fmaxf(c2 + b2l, 0.f), h3 = fmaxf(c3 + b2l, 0.f);
            h[(size_t)(r0 + 0) * 64 + lane] = h0;
            h[(size_t)(r0 + 1) * 64 + lane] = h1;
            h[(size_t)(r0 + 2) * 64 + lane] = h2;
            h[(size_t)(r0 + 3) * 64 + lane] = h3;
            hb[(size_t)(r0 + 0) * 64 + lane] = f2bf(h0);
            hb[(size_t)(r0 + 1) * 64 + lane] = f2bf(h1);
            hb[(size_t)(r0 + 2) * 64 + lane] = f2bf(h2);
            hb[(size_t)(r0 + 3) * 64 + lane] = f2bf(h3);
        } else {
            for (int r = r0; r < N; ++r) {
                const float* xr = x + (size_t)r * C;
                float acc = 0.f;
                for (int k4 = 0; k4 < C / 4; ++k4) {
                    float4 wv = *(const float4*)(wr1 + k4 * 4);
                    float4 v = *(const float4*)(xr + k4 * 4);
                    acc = fmaf(wv.x, v.x, acc); acc = fmaf(wv.y, v.y, acc);
                    acc = fmaf(wv.z, v.z, acc); acc = fmaf(wv.w, v.w, acc);
                }
                float t = fmaxf(acc + b1l, 0.f);
                float acc2 = 0.f;
                #pragma unroll
                for (int k4 = 0; k4 < 16; ++k4) {
                    float4 wv = *(const float4*)(wr2 + k4 * 4);
                    acc2 = fmaf(wv.x, __shfl(t, k4 * 4 + 0, 64), acc2);
                    acc2 = fmaf(wv.y, __shfl(t, k4 * 4 + 1, 64), acc2);
                    acc2 = fmaf(wv.z, __shfl(t, k4 * 4 + 2, 64), acc2);
                    acc2 = fmaf(wv.w, __shfl(t, k4 * 4 + 3, 64), acc2);
                }
                float hv = fmaxf(acc2 + b2l, 0.f);
                h[(size_t)r * 64 + lane] = hv;
                hb[(size_t)r * 64 + lane] = f2bf(hv);
            }
        }
    }
}

// ---- CSR build (once per call, reused by both layers) ----
__global__ __launch_bounds__(256) void hist_kernel(
    const int* __restrict__ dst, int* __restrict__ cnt, int E) {
    for (int e = blockIdx.x * blockDim.x + threadIdx.x; e < E;
         e += gridDim.x * blockDim.x)
        atomicAdd(&cnt[dst[e]], 1);
}

// single-block exclusive scan: cnt[N] -> row_ptr[N+1]
__global__ __launch_bounds__(1024) void scan_kernel(
    const int* __restrict__ cnt, int* __restrict__ row_ptr, int N) {
    __shared__ int sums[1024];
    const int tid = threadIdx.x;
    const int chunk = (N + 1023) / 1024;
    const int beg = tid * chunk;
    const int end = min(beg + chunk, N);
    int s = 0;
    for (int i = beg; i < end; ++i) s += cnt[i];
    sums[tid] = s;
    __syncthreads();
    for (int off = 1; off < 1024; off <<= 1) {
        int v = (tid >= off) ? sums[tid - off] : 0;
        __syncthreads();
        sums[tid] += v;
        __syncthreads();
    }
    int run = (tid == 0) ? 0 : sums[tid - 1];
    for (int i = beg; i < end; ++i) {
        row_ptr[i] = run;
        run += cnt[i];
    }
    if (tid == 1023) row_ptr[N] = sums[1023];
}

// fill dst-grouped records: (src, dst, base_w*sig(rr_s)*sig(rr_d), pad)
__global__ __launch_bounds__(256) void scatter_kernel(
    const int* __restrict__ src, const int* __restrict__ dst,
    const float* __restrict__ base_w, const float* __restrict__ rr,
    const int* __restrict__ row_ptr, int* __restrict__ fill,
    int4* __restrict__ recs, int E) {
    for (int e = blockIdx.x * blockDim.x + threadIdx.x; e < E;
         e += gridDim.x * blockDim.x) {
        int s = src[e], d = dst[e];
        int pos = row_ptr[d] + atomicAdd(&fill[d], 1);
        float rs = 1.f / (1.f + __expf(-rr[s]));
        float rd = 1.f / (1.f + __expf(-rr[d]));
        float c = base_w[e] * rs * rd;
        recs[pos] = make_int4(s, d, __float_as_int(c), 0);
    }
}

// gate projection: ab = bf16(h@gw1[0:64]+gb1), bbuf = h@gw1[64:128]
// transposed weights: gw1t[lane][0..63]=a-cols, [64..127]=b-cols.
__global__ __launch_bounds__(256) void gateproj_kernel(
    const float* __restrict__ h, const float* __restrict__ gw1t,
    const float* __restrict__ gb1, ushort_t* __restrict__ ab,
    float* __restrict__ bbuf, int N) {
    const int lane = threadIdx.x & 63;
    const int wid  = blockIdx.x * (blockDim.x >> 6) + (threadIdx.x >> 6);
    const int nw   = gridDim.x * (blockDim.x >> 6);
    const float gbl = gb1[lane];
    const float* gar = gw1t + (size_t)lane * 128;
    for (int r = wid; r < N; r += nw) {
        float hv = h[(size_t)r * 64 + lane];
        float aa = 0.f, bv = 0.f;
        #pragma unroll
        for (int k4 = 0; k4 < 16; ++k4) {
            float4 ga  = *(const float4*)(gar + k4 * 4);
            float4 gb_ = *(const float4*)(gar + 64 + k4 * 4);
            float e0 = __shfl(hv, k4 * 4 + 0, 64);
            float e1 = __shfl(hv, k4 * 4 + 1, 64);
            float e2 = __shfl(hv, k4 * 4 + 2, 64);
            float e3 = __shfl(hv, k4 * 4 + 3, 64);
            aa = fmaf(ga.x, e0, aa);  bv = fmaf(gb_.x, e0, bv);
            aa = fmaf(ga.y, e1, aa);  bv = fmaf(gb_.y, e1, bv);
            aa = fmaf(ga.z, e2, aa);  bv = fmaf(gb_.z, e2, bv);
            aa = fmaf(ga.w, e3, aa);  bv = fmaf(gb_.w, e3, bv);
        }
        ab[(size_t)r * 64 + lane] = f2bf(aa + gbl);
        bbuf[(size_t)r * 64 + lane] = bv;
    }
}

// 16 lanes per edge: z = relu(a[s]+bb[d]) dot gw2 (4 elems/lane, 4-step reduce)
// w = c * sigmoid(z + gb2);  sw[e] = (s, w).  a gathered as bf16 (8B/lane).
__global__ __launch_bounds__(256) void gate_kernel(
    const int4* __restrict__ recs, const ushort_t* __restrict__ ab,
    const float* __restrict__ bb, const float* __restrict__ gw2,
    const float* __restrict__ gb2, int2* __restrict__ sw, int E) {
    const int lane = threadIdx.x & 63;
    const int sub  = lane & 15;                       // feature slice id
    const float4 gv = ((const float4*)gw2)[sub];
    const float gb = gb2[0];
    int grp  = (blockIdx.x * blockDim.x + threadIdx.x) >> 4;
    const int ngrp = (gridDim.x * blockDim.x) >> 4;
    for (int e = grp; e < E; e += ngrp) {
        int4 r = recs[e];                             // broadcast within group
        ushort4 av = ((const ushort4*)(ab + (size_t)r.x * 64))[sub];
        float4 bv = ((const float4*)(bb + (size_t)r.y * 64))[sub];
        float t = fmaxf(bf2f(av.x) + bv.x, 0.f) * gv.x
                + fmaxf(bf2f(av.y) + bv.y, 0.f) * gv.y
                + fmaxf(bf2f(av.z) + bv.z, 0.f) * gv.z
                + fmaxf(bf2f(av.w) + bv.w, 0.f) * gv.w;
        #pragma unroll
        for (int o = 8; o > 0; o >>= 1) t += __shfl_xor(t, o, 64);
        float w = __int_as_float(r.z) / (1.f + __expf(-(t + gb)));
        if (sub == 0) sw[e] = make_int2(r.x, __float_as_int(w));
    }
}

// wave-per-node: gather+fma aggregation over bf16 h rows (16-deep batches),
// fused update MLP + LayerNorm in fp32 with transposed weights.
__global__ __launch_bounds__(256) void agg_update_kernel(
    const int* __restrict__ row_ptr, const int2* __restrict__ sw,
    const ushort_t* __restrict__ hb_in, const float* __restrict__ h_in,
    const float* __restrict__ u1t, const float* __restrict__ b1,
    const float* __restrict__ u2t, const float* __restrict__ b2,
    const float* __restrict__ lng, const float* __restrict__ lnb,
    float* __restrict__ h_out, ushort_t* __restrict__ hb_out, int N) {
    const int lane = threadIdx.x & 63;
    const int wid  = blockIdx.x * (blockDim.x >> 6) + (threadIdx.x >> 6);
    const int nw   = gridDim.x * (blockDim.x >> 6);
    const float b1l = b1[lane], b2l = b2[lane];
    const float gl = lng[lane], bl = lnb[lane];
    const float* u1r = u1t + (size_t)lane * 64;
    const float* u2r = u2t + (size_t)lane * 64;
    for (int n = wid; n < N; n += nw) {
        const int beg = row_ptr[n], end = row_ptr[n + 1];
        float macc = 0.f, dacc = 0.f;
        int i = beg;
        for (; i + 16 <= end; i += 16) {
            float wv[16], hv[16];
            #pragma unroll
            for (int j = 0; j < 16; ++j) {
                int2 r = sw[i + j];
                wv[j] = __int_as_float(r.y);
                hv[j] = bf2f(hb_in[(size_t)r.x * 64 + lane]);
            }
            #pragma unroll
            for (int j = 0; j < 16; ++j) {
                macc = fmaf(wv[j], hv[j], macc);
                dacc += wv[j];
            }
        }
        for (; i + 4 <= end; i += 4) {
            float wv[4], hv[4];
            #pragma unroll
            for (int j = 0; j < 4; ++j) {
                int2 r = sw[i + j];
                wv[j] = __int_as_float(r.y);
                hv[j] = bf2f(hb_in[(size_t)r.x * 64 + lane]);
            }
            #pragma unroll
            for (int j = 0; j < 4; ++j) {
                macc = fmaf(wv[j], hv[j], macc);
                dacc += wv[j];
            }
        }
        for (; i < end; ++i) {
            int2 r = sw[i];
            float w0 = __int_as_float(r.y);
            macc = fmaf(w0, bf2f(hb_in[(size_t)r.x * 64 + lane]), macc);
            dacc += w0;
        }
        // ---- fused update MLP + LayerNorm ----
        float neigh = macc / (dacc + 1e-8f);
        float acc = 0.f;
        #pragma unroll
        for (int k4 = 0; k4 < 16; ++k4) {
            float4 wv = *(const float4*)(u1r + k4 * 4);
            acc = fmaf(wv.x, __shfl(neigh, k4 * 4 + 0, 64), acc);
            acc = fmaf(wv.y, __shfl(neigh, k4 * 4 + 1, 64), acc);
            acc = fmaf(wv.z, __shfl(neigh, k4 * 4 + 2, 64), acc);
            acc = fmaf(wv.w, __shfl(neigh, k4 * 4 + 3, 64), acc);
        }
        float t = fmaxf(acc + b1l, 0.f);
        float acc2 = 0.f;
        #pragma unroll
        for (int k4 = 0; k4 < 16; ++k4) {
            float4 wv = *(const float4*)(u2r + k4 * 4);
            acc2 = fmaf(wv.x, __shfl(t, k4 * 4 + 0, 64), acc2);
            acc2 = fmaf(wv.y, __shfl(t, k4 * 4 + 1, 64), acc2);
            acc2 = fmaf(wv.z, __shfl(t, k4 * 4 + 2, 64), acc2);
            acc2 = fmaf(wv.w, __shfl(t, k4 * 4 + 3, 64), acc2);
        }
        float pre = h_in[(size_t)n * 64 + lane] + acc2 + b2l;
        float s1 = wave_sum64(pre);
        float s2 = wave_sum64(pre * pre);
        float mean = s1 * (1.0f / 64.0f);
        float var  = s2 * (1.0f / 64.0f) - mean * mean;
        float hn = (pre - mean) * rsqrtf(var + 1e-5f) * gl + bl;
        h_out[(size_t)n * 64 + lane] = hn;
        hb_out[(size_t)n * 64 + lane] = f2bf(hn);
    }
}

// U = softplus(h @ toU_w + toU_b), K=32
__global__ __launch_bounds__(256) void out_kernel(
    const float* __restrict__ h, const float* __restrict__ tw,
    const float* __restrict__ tb, float* __restrict__ U, int N) {
    int gid = blockIdx.x * blockDim.x + threadIdx.x;
    int n = gid >> 5;
    int k = gid & 31;
    if (n >= N) return;
    float acc = tb[k];
    const float* hr = h + (size_t)n * 64;
    #pragma unroll 8
    for (int j = 0; j < 64; ++j) acc = fmaf(hr[j], tw[j * 32 + k], acc);
    float sp = acc > 0.f ? acc + log1pf(__expf(-acc)) : log1pf(__expf(acc));
    U[(size_t)n * 32 + k] = sp;
}

extern "C" void kernel_launch(void* const* d_in, const int* in_sizes, int n_in,
                              void* d_out, int out_size, void* d_ws, size_t ws_size,
                              hipStream_t stream) {
    const float* x       = (const float*)d_in[0];
    const int*   src     = (const int*)d_in[1];
    const int*   dst     = (const int*)d_in[2];
    const float* base_w  = (const float*)d_in[3];
    const float* enc_w1  = (const float*)d_in[4];
    const float* enc_b1  = (const float*)d_in[5];
    const float* enc_w2  = (const float*)d_in[6];
    const float* enc_b2  = (const float*)d_in[7];
    const float* gate_w1 = (const float*)d_in[8];
    const float* gate_b1 = (const float*)d_in[9];
    const float* gate_w2 = (const float*)d_in[10];
    const float* gate_b2 = (const float*)d_in[11];
    const float* upd_w1  = (const float*)d_in[12];
    const float* upd_b1  = (const float*)d_in[13];
    const float* upd_w2  = (const float*)d_in[14];
    const float* upd_b2  = (const float*)d_in[15];
    const float* ln_g    = (const float*)d_in[16];
    const float* ln_b    = (const float*)d_in[17];
    const float* rho_raw = (const float*)d_in[18];
    const float* toU_w   = (const float*)d_in[19];
    const float* toU_b   = (const float*)d_in[20];

    const int N = in_sizes[18];          // 50000
    const int C = in_sizes[0] / N;       // 256
    const int E = in_sizes[1];           // 800000
    const int L = 2;

    // workspace layout (float units), sections padded to 16B alignment
    float* ws  = (float*)d_ws;
    size_t off = 0;
    float* h0  = ws + off; off += (size_t)N * 64;
    float* h1  = ws + off; off += (size_t)N * 64;
    ushort_t* hb0 = (ushort_t*)(ws + off); off += (size_t)N * 32;
    ushort_t* hb1 = (ushort_t*)(ws + off); off += (size_t)N * 32;
    ushort_t* ab  = (ushort_t*)(ws + off); off += (size_t)N * 32;
    float* bb  = ws + off; off += (size_t)N * 64;
    int* row_ptr = (int*)(ws + off); off += (size_t)((N + 1 + 3) & ~3);
    int* cnt     = (int*)(ws + off); off += (size_t)((N + 3) & ~3);
    int4* recs   = (int4*)(ws + off); off += (size_t)E * 4;   // (s,d,c,0)
    int2* sw     = (int2*)(ws + off); off += (size_t)E * 2;   // (s,w)
    float* w1t   = ws + off; off += 64 * 256;
    float* w2t   = ws + off; off += 64 * 64;
    float* gw1t  = ws + off; off += 64 * 128;
    float* uw1t  = ws + off; off += 2 * 64 * 64;
    float* uw2t  = ws + off; off += 2 * 64 * 64;

    // one-time weight transposes (16384 is the largest section)
    wtrans_kernel<<<64, 256, 0, stream>>>(enc_w1, enc_w2, gate_w1, upd_w1, upd_w2,
                                          w1t, w2t, gw1t, uw1t, uw2t);

    enc_kernel<<<1563, 256, 0, stream>>>(x, w1t, enc_b1, w2t, enc_b2,
                                         h0, hb0, N, C);

    // CSR build (dst-sorted edge records); rho folded into scatter
    hipMemsetAsync(cnt, 0, (size_t)N * sizeof(int), stream);
    hist_kernel<<<(E + 255) / 256, 256, 0, stream>>>(dst, cnt, E);
    scan_kernel<<<1, 1024, 0, stream>>>(cnt, row_ptr, N);
    hipMemsetAsync(cnt, 0, (size_t)N * sizeof(int), stream);
    scatter_kernel<<<(E + 255) / 256, 256, 0, stream>>>(src, dst, base_w, rho_raw,
                                                        row_ptr, cnt, recs, E);

    float* h_cur = h0;  ushort_t* hb_cur = hb0;
    float* h_nxt = h1;  ushort_t* hb_nxt = hb1;
    for (int l = 0; l < L; ++l) {
        gateproj_kernel<<<1024, 256, 0, stream>>>(h_cur, gw1t, gate_b1, ab, bb, N);
        gate_kernel<<<4096, 256, 0, stream>>>(recs, ab, bb, gate_w2, gate_b2, sw, E);
        agg_update_kernel<<<2048, 256, 0, stream>>>(
            row_ptr, sw, hb_cur, h_cur,
            uw1t + (size_t)l * 4096, upd_b1 + l * 64,
            uw2t + (size_t)l * 4096, upd_b2 + l * 64,
            ln_g + l * 64, ln_b + l * 64, h_nxt, hb_nxt, N);
        float* tf = h_cur; h_cur = h_nxt; h_nxt = tf;
        ushort_t* tb2 = hb_cur; hb_cur = hb_nxt; hb_nxt = tb2;
    }

    out_kernel<<<((N * 32) + 255) / 256, 256, 0, stream>>>(h_cur, toU_w, toU_b,
                                                           (float*)d_out, N);
}

// Round 9
// 707.640 us; speedup vs baseline: 1.2247x; 1.2247x over previous
//
#include <hip/hip_runtime.h>
#include <math.h>

// ---------------------------------------------------------------------------
// StageA GNN: encoder -> CSR build -> L x (gateproj, gate, agg+update+LN) -> head
// R9: revert ALL R8 weight transposes (lane-major = broken cross-lane
// coalescing, 64 cache lines/instr). enc rebuilt: W1 (64KB) + x tile (16KB)
// both staged in LDS -> kills the 3.2GB W1 L2 re-read AND the x broadcast
// latency. All other kernels are the proven R7 versions (k-major weights,
// coalesced across lanes, L1-hot).
// ---------------------------------------------------------------------------

typedef unsigned short ushort_t;

__device__ __forceinline__ float bf2f(ushort_t u) {
    return __uint_as_float(((unsigned int)u) << 16);
}
__device__ __forceinline__ ushort_t f2bf(float f) {
    unsigned int x = __float_as_uint(f);
    unsigned int lsb = (x >> 16) & 1u;
    x += 0x7fffu + lsb;                 // round-to-nearest-even
    return (ushort_t)(x >> 16);
}

__device__ __forceinline__ float wave_sum64(float v) {
    #pragma unroll
    for (int o = 32; o > 0; o >>= 1) v += __shfl_xor(v, o, 64);
    return v;
}

// h = relu(relu(x@W1+b1)@W2+b2).
// W1 in LDS (64KB, k-major [k][n]); x staged per 16-row tile (16KB) via
// coalesced float4 copies; each wave computes 4 rows with interleaved
// accumulator chains. w2 (16KB) stays global (L1-hot, coalesced).
__global__ __launch_bounds__(256) void enc_kernel(
    const float* __restrict__ x, const float* __restrict__ w1,
    const float* __restrict__ b1, const float* __restrict__ w2,
    const float* __restrict__ b2,
    float* __restrict__ h, ushort_t* __restrict__ hb, int N, int C) {
    __shared__ float ws1[256 * 64];   // 64 KB
    __shared__ float xs[16 * 256];    // 16 KB
    const int tid  = threadIdx.x;
    const int lane = tid & 63;
    const int wvid = tid >> 6;        // 0..3
    const float b1l = b1[lane], b2l = b2[lane];
    for (int i = tid; i < 256 * 64; i += 256) ws1[i] = w1[i];
    const int ntile = (N + 15) >> 4;
    for (int tile = blockIdx.x; tile < ntile; tile += gridDim.x) {
        const int rbase = tile << 4;
        const int rows = min(16, N - rbase);
        __syncthreads();              // previous tile fully consumed
        {   // coalesced stage: rows*64 float4
            const float4* s4 = (const float4*)(x + (size_t)rbase * 256);
            float4* d4 = (float4*)xs;
            for (int i = tid; i < rows * 64; i += 256) d4[i] = s4[i];
        }
        __syncthreads();
        const int r0 = wvid * 4;
        if (r0 + 4 <= rows) {
            const float* xr = xs + r0 * 256;
            float s0 = 0.f, s1 = 0.f, s2 = 0.f, s3 = 0.f;
            #pragma unroll 8
            for (int k4 = 0; k4 < 64; ++k4) {
                const float* wp = ws1 + k4 * 256 + lane;
                float wa = wp[0], wbv = wp[64], wc = wp[128], wd = wp[192];
                float4 v0 = *(const float4*)(xr + k4 * 4);
                float4 v1 = *(const float4*)(xr + 256 + k4 * 4);
                float4 v2 = *(const float4*)(xr + 512 + k4 * 4);
                float4 v3 = *(const float4*)(xr + 768 + k4 * 4);
                s0 = fmaf(wa, v0.x, s0); s0 = fmaf(wbv, v0.y, s0);
                s0 = fmaf(wc, v0.z, s0); s0 = fmaf(wd, v0.w, s0);
                s1 = fmaf(wa, v1.x, s1); s1 = fmaf(wbv, v1.y, s1);
                s1 = fmaf(wc, v1.z, s1); s1 = fmaf(wd, v1.w, s1);
                s2 = fmaf(wa, v2.x, s2); s2 = fmaf(wbv, v2.y, s2);
                s2 = fmaf(wc, v2.z, s2); s2 = fmaf(wd, v2.w, s2);
                s3 = fmaf(wa, v3.x, s3); s3 = fmaf(wbv, v3.y, s3);
                s3 = fmaf(wc, v3.z, s3); s3 = fmaf(wd, v3.w, s3);
            }
            float t0 = fmaxf(s0 + b1l, 0.f), t1 = fmaxf(s1 + b1l, 0.f);
            float t2 = fmaxf(s2 + b1l, 0.f), t3 = fmaxf(s3 + b1l, 0.f);
            float c0 = 0.f, c1 = 0.f, c2 = 0.f, c3 = 0.f;
            #pragma unroll
            for (int k = 0; k < 64; ++k) {
                float wv = w2[(size_t)k * 64 + lane];
                c0 = fmaf(wv, __shfl(t0, k, 64), c0);
                c1 = fmaf(wv, __shfl(t1, k, 64), c1);
                c2 = fmaf(wv, __shfl(t2, k, 64), c2);
                c3 = fmaf(wv, __shfl(t3, k, 64), c3);
            }
            float h0 = fmaxf(c0 + b2l, 0.f), h1 = fmaxf(c1 + b2l, 0.f);
            float h2 = fmaxf(c2 + b2l, 0.f), h3 = fmaxf(c3 + b2l, 0.f);
            const int r = rbase + r0;
            h[(size_t)(r + 0) * 64 + lane] = h0;
            h[(size_t)(r + 1) * 64 + lane] = h1;
            h[(size_t)(r + 2) * 64 + lane] = h2;
            h[(size_t)(r + 3) * 64 + lane] = h3;
            hb[(size_t)(r + 0) * 64 + lane] = f2bf(h0);
            hb[(size_t)(r + 1) * 64 + lane] = f2bf(h1);
            hb[(size_t)(r + 2) * 64 + lane] = f2bf(h2);
            hb[(size_t)(r + 3) * 64 + lane] = f2bf(h3);
        } else {
            for (int rr = r0; rr < min(r0 + 4, rows); ++rr) {
                const float* xr = xs + rr * 256;
                float acc = 0.f;
                #pragma unroll 8
                for (int k4 = 0; k4 < 64; ++k4) {
                    const float* wp = ws1 + k4 * 256 + lane;
                    float4 v = *(const float4*)(xr + k4 * 4);
                    acc = fmaf(wp[0],   v.x, acc);
                    acc = fmaf(wp[64],  v.y, acc);
                    acc = fmaf(wp[128], v.z, acc);
                    acc = fmaf(wp[192], v.w, acc);
                }
                float t = fmaxf(acc + b1l, 0.f);
                float acc2 = 0.f;
                #pragma unroll
                for (int k = 0; k < 64; ++k)
                    acc2 = fmaf(w2[(size_t)k * 64 + lane], __shfl(t, k, 64), acc2);
                float hv = fmaxf(acc2 + b2l, 0.f);
                const int r = rbase + rr;
                h[(size_t)r * 64 + lane] = hv;
                hb[(size_t)r * 64 + lane] = f2bf(hv);
            }
        }
    }
}

// ---- CSR build (once per call, reused by both layers) ----
__global__ __launch_bounds__(256) void hist_kernel(
    const int* __restrict__ dst, int* __restrict__ cnt, int E) {
    for (int e = blockIdx.x * blockDim.x + threadIdx.x; e < E;
         e += gridDim.x * blockDim.x)
        atomicAdd(&cnt[dst[e]], 1);
}

// single-block exclusive scan: cnt[N] -> row_ptr[N+1]
__global__ __launch_bounds__(1024) void scan_kernel(
    const int* __restrict__ cnt, int* __restrict__ row_ptr, int N) {
    __shared__ int sums[1024];
    const int tid = threadIdx.x;
    const int chunk = (N + 1023) / 1024;
    const int beg = tid * chunk;
    const int end = min(beg + chunk, N);
    int s = 0;
    for (int i = beg; i < end; ++i) s += cnt[i];
    sums[tid] = s;
    __syncthreads();
    for (int off = 1; off < 1024; off <<= 1) {
        int v = (tid >= off) ? sums[tid - off] : 0;
        __syncthreads();
        sums[tid] += v;
        __syncthreads();
    }
    int run = (tid == 0) ? 0 : sums[tid - 1];
    for (int i = beg; i < end; ++i) {
        row_ptr[i] = run;
        run += cnt[i];
    }
    if (tid == 1023) row_ptr[N] = sums[1023];
}

// fill dst-grouped records: (src, dst, base_w*sig(rr_s)*sig(rr_d), pad)
__global__ __launch_bounds__(256) void scatter_kernel(
    const int* __restrict__ src, const int* __restrict__ dst,
    const float* __restrict__ base_w, const float* __restrict__ rr,
    const int* __restrict__ row_ptr, int* __restrict__ fill,
    int4* __restrict__ recs, int E) {
    for (int e = blockIdx.x * blockDim.x + threadIdx.x; e < E;
         e += gridDim.x * blockDim.x) {
        int s = src[e], d = dst[e];
        int pos = row_ptr[d] + atomicAdd(&fill[d], 1);
        float rs = 1.f / (1.f + __expf(-rr[s]));
        float rd = 1.f / (1.f + __expf(-rr[d]));
        float c = base_w[e] * rs * rd;
        recs[pos] = make_int4(s, d, __float_as_int(c), 0);
    }
}

// gate projection: ab = bf16(h@gw1[0:64]+gb1), bbuf = h@gw1[64:128]; k-major
// gw1 reads (coalesced across lanes, L1-hot). R7 version.
__global__ __launch_bounds__(256) void gateproj_kernel(
    const float* __restrict__ h, const float* __restrict__ gw1,
    const float* __restrict__ gb1, ushort_t* __restrict__ ab,
    float* __restrict__ bbuf, int N) {
    const int lane = threadIdx.x & 63;
    const int wid  = blockIdx.x * (blockDim.x >> 6) + (threadIdx.x >> 6);
    const int nw   = gridDim.x * (blockDim.x >> 6);
    const float gbl = gb1[lane];
    for (int r = wid; r < N; r += nw) {
        float hv = h[(size_t)r * 64 + lane];
        float aa = 0.f, bv = 0.f;
        #pragma unroll
        for (int k = 0; k < 64; ++k) {
            float tv = __shfl(hv, k, 64);
            aa = fmaf(gw1[(size_t)k * 64 + lane], tv, aa);
            bv = fmaf(gw1[(size_t)(64 + k) * 64 + lane], tv, bv);
        }
        ab[(size_t)r * 64 + lane] = f2bf(aa + gbl);
        bbuf[(size_t)r * 64 + lane] = bv;
    }
}

// 16 lanes per edge: z = relu(a[s]+bb[d]) dot gw2 (4 elems/lane, 4-step reduce)
// w = c * sigmoid(z + gb2);  sw[e] = (s, w).  a gathered as bf16 (8B/lane).
__global__ __launch_bounds__(256) void gate_kernel(
    const int4* __restrict__ recs, const ushort_t* __restrict__ ab,
    const float* __restrict__ bb, const float* __restrict__ gw2,
    const float* __restrict__ gb2, int2* __restrict__ sw, int E) {
    const int lane = threadIdx.x & 63;
    const int sub  = lane & 15;                       // feature slice id
    const float4 gv = ((const float4*)gw2)[sub];
    const float gb = gb2[0];
    int grp  = (blockIdx.x * blockDim.x + threadIdx.x) >> 4;
    const int ngrp = (gridDim.x * blockDim.x) >> 4;
    for (int e = grp; e < E; e += ngrp) {
        int4 r = recs[e];                             // broadcast within group
        ushort4 av = ((const ushort4*)(ab + (size_t)r.x * 64))[sub];
        float4 bv = ((const float4*)(bb + (size_t)r.y * 64))[sub];
        float t = fmaxf(bf2f(av.x) + bv.x, 0.f) * gv.x
                + fmaxf(bf2f(av.y) + bv.y, 0.f) * gv.y
                + fmaxf(bf2f(av.z) + bv.z, 0.f) * gv.z
                + fmaxf(bf2f(av.w) + bv.w, 0.f) * gv.w;
        #pragma unroll
        for (int o = 8; o > 0; o >>= 1) t += __shfl_xor(t, o, 64);
        float w = __int_as_float(r.z) / (1.f + __expf(-(t + gb)));
        if (sub == 0) sw[e] = make_int2(r.x, __float_as_int(w));
    }
}

// wave-per-node: gather+fma aggregation over bf16 h rows (8-deep unroll, no
// cross-lane ops in loop), fused update MLP + LayerNorm in fp32.
// k-major weights from global (L1-hot, coalesced). R7 version.
__global__ __launch_bounds__(256) void agg_update_kernel(
    const int* __restrict__ row_ptr, const int2* __restrict__ sw,
    const ushort_t* __restrict__ hb_in, const float* __restrict__ h_in,
    const float* __restrict__ w1, const float* __restrict__ b1,
    const float* __restrict__ w2, const float* __restrict__ b2,
    const float* __restrict__ lng, const float* __restrict__ lnb,
    float* __restrict__ h_out, ushort_t* __restrict__ hb_out, int N) {
    const int lane = threadIdx.x & 63;
    const int wid  = blockIdx.x * (blockDim.x >> 6) + (threadIdx.x >> 6);
    const int nw   = gridDim.x * (blockDim.x >> 6);
    const float b1l = b1[lane], b2l = b2[lane];
    const float gl = lng[lane], bl = lnb[lane];
    for (int n = wid; n < N; n += nw) {
        const int beg = row_ptr[n], end = row_ptr[n + 1];
        float macc = 0.f, dacc = 0.f;
        int i = beg;
        for (; i + 8 <= end; i += 8) {
            int2 r0 = sw[i],     r1 = sw[i + 1], r2 = sw[i + 2], r3 = sw[i + 3];
            int2 r4 = sw[i + 4], r5 = sw[i + 5], r6 = sw[i + 6], r7 = sw[i + 7];
            float hv0 = bf2f(hb_in[(size_t)r0.x * 64 + lane]);
            float hv1 = bf2f(hb_in[(size_t)r1.x * 64 + lane]);
            float hv2 = bf2f(hb_in[(size_t)r2.x * 64 + lane]);
            float hv3 = bf2f(hb_in[(size_t)r3.x * 64 + lane]);
            float hv4 = bf2f(hb_in[(size_t)r4.x * 64 + lane]);
            float hv5 = bf2f(hb_in[(size_t)r5.x * 64 + lane]);
            float hv6 = bf2f(hb_in[(size_t)r6.x * 64 + lane]);
            float hv7 = bf2f(hb_in[(size_t)r7.x * 64 + lane]);
            float w0 = __int_as_float(r0.y), w1v = __int_as_float(r1.y);
            float w2v = __int_as_float(r2.y), w3v = __int_as_float(r3.y);
            float w4v = __int_as_float(r4.y), w5v = __int_as_float(r5.y);
            float w6v = __int_as_float(r6.y), w7v = __int_as_float(r7.y);
            macc = fmaf(w0, hv0, macc);  macc = fmaf(w1v, hv1, macc);
            macc = fmaf(w2v, hv2, macc); macc = fmaf(w3v, hv3, macc);
            macc = fmaf(w4v, hv4, macc); macc = fmaf(w5v, hv5, macc);
            macc = fmaf(w6v, hv6, macc); macc = fmaf(w7v, hv7, macc);
            dacc += ((w0 + w1v) + (w2v + w3v)) + ((w4v + w5v) + (w6v + w7v));
        }
        for (; i < end; ++i) {
            int2 r0 = sw[i];
            float hv0 = bf2f(hb_in[(size_t)r0.x * 64 + lane]);
            float w0 = __int_as_float(r0.y);
            macc = fmaf(w0, hv0, macc);
            dacc += w0;
        }
        // ---- fused update MLP + LayerNorm ----
        float neigh = macc / (dacc + 1e-8f);
        float acc = 0.f;
        #pragma unroll
        for (int k = 0; k < 64; ++k) {
            float tv = __shfl(neigh, k, 64);
            acc = fmaf(w1[(size_t)k * 64 + lane], tv, acc);
        }
        float t = fmaxf(acc + b1l, 0.f);
        float acc2 = 0.f;
        #pragma unroll
        for (int k = 0; k < 64; ++k) {
            float tv = __shfl(t, k, 64);
            acc2 = fmaf(w2[(size_t)k * 64 + lane], tv, acc2);
        }
        float pre = h_in[(size_t)n * 64 + lane] + acc2 + b2l;
        float s1 = wave_sum64(pre);
        float s2 = wave_sum64(pre * pre);
        float mean = s1 * (1.0f / 64.0f);
        float var  = s2 * (1.0f / 64.0f) - mean * mean;
        float hn = (pre - mean) * rsqrtf(var + 1e-5f) * gl + bl;
        h_out[(size_t)n * 64 + lane] = hn;
        hb_out[(size_t)n * 64 + lane] = f2bf(hn);
    }
}

// U = softplus(h @ toU_w + toU_b), K=32
__global__ __launch_bounds__(256) void out_kernel(
    const float* __restrict__ h, const float* __restrict__ tw,
    const float* __restrict__ tb, float* __restrict__ U, int N) {
    int gid = blockIdx.x * blockDim.x + threadIdx.x;
    int n = gid >> 5;
    int k = gid & 31;
    if (n >= N) return;
    float acc = tb[k];
    const float* hr = h + (size_t)n * 64;
    #pragma unroll 8
    for (int j = 0; j < 64; ++j) acc = fmaf(hr[j], tw[j * 32 + k], acc);
    float sp = acc > 0.f ? acc + log1pf(__expf(-acc)) : log1pf(__expf(acc));
    U[(size_t)n * 32 + k] = sp;
}

extern "C" void kernel_launch(void* const* d_in, const int* in_sizes, int n_in,
                              void* d_out, int out_size, void* d_ws, size_t ws_size,
                              hipStream_t stream) {
    const float* x       = (const float*)d_in[0];
    const int*   src     = (const int*)d_in[1];
    const int*   dst     = (const int*)d_in[2];
    const float* base_w  = (const float*)d_in[3];
    const float* enc_w1  = (const float*)d_in[4];
    const float* enc_b1  = (const float*)d_in[5];
    const float* enc_w2  = (const float*)d_in[6];
    const float* enc_b2  = (const float*)d_in[7];
    const float* gate_w1 = (const float*)d_in[8];
    const float* gate_b1 = (const float*)d_in[9];
    const float* gate_w2 = (const float*)d_in[10];
    const float* gate_b2 = (const float*)d_in[11];
    const float* upd_w1  = (const float*)d_in[12];
    const float* upd_b1  = (const float*)d_in[13];
    const float* upd_w2  = (const float*)d_in[14];
    const float* upd_b2  = (const float*)d_in[15];
    const float* ln_g    = (const float*)d_in[16];
    const float* ln_b    = (const float*)d_in[17];
    const float* rho_raw = (const float*)d_in[18];
    const float* toU_w   = (const float*)d_in[19];
    const float* toU_b   = (const float*)d_in[20];

    const int N = in_sizes[18];          // 50000
    const int C = in_sizes[0] / N;       // 256
    const int E = in_sizes[1];           // 800000
    const int L = 2;

    // workspace layout (float units), sections padded to 16B alignment
    float* ws  = (float*)d_ws;
    size_t off = 0;
    float* h0  = ws + off; off += (size_t)N * 64;
    float* h1  = ws + off; off += (size_t)N * 64;
    ushort_t* hb0 = (ushort_t*)(ws + off); off += (size_t)N * 32;
    ushort_t* hb1 = (ushort_t*)(ws + off); off += (size_t)N * 32;
    ushort_t* ab  = (ushort_t*)(ws + off); off += (size_t)N * 32;
    float* bb  = ws + off; off += (size_t)N * 64;
    int* row_ptr = (int*)(ws + off); off += (size_t)((N + 1 + 3) & ~3);
    int* cnt     = (int*)(ws + off); off += (size_t)((N + 3) & ~3);
    int4* recs   = (int4*)(ws + off); off += (size_t)E * 4;   // (s,d,c,0)
    int2* sw     = (int2*)(ws + off); off += (size_t)E * 2;   // (s,w)

    enc_kernel<<<1024, 256, 0, stream>>>(x, enc_w1, enc_b1, enc_w2, enc_b2,
                                         h0, hb0, N, C);

    // CSR build (dst-sorted edge records); rho folded into scatter
    hipMemsetAsync(cnt, 0, (size_t)N * sizeof(int), stream);
    hist_kernel<<<(E + 255) / 256, 256, 0, stream>>>(dst, cnt, E);
    scan_kernel<<<1, 1024, 0, stream>>>(cnt, row_ptr, N);
    hipMemsetAsync(cnt, 0, (size_t)N * sizeof(int), stream);
    scatter_kernel<<<(E + 255) / 256, 256, 0, stream>>>(src, dst, base_w, rho_raw,
                                                        row_ptr, cnt, recs, E);

    float* h_cur = h0;  ushort_t* hb_cur = hb0;
    float* h_nxt = h1;  ushort_t* hb_nxt = hb1;
    for (int l = 0; l < L; ++l) {
        gateproj_kernel<<<1024, 256, 0, stream>>>(h_cur, gate_w1, gate_b1,
                                                  ab, bb, N);
        gate_kernel<<<4096, 256, 0, stream>>>(recs, ab, bb, gate_w2, gate_b2, sw, E);
        agg_update_kernel<<<2048, 256, 0, stream>>>(
            row_ptr, sw, hb_cur, h_cur,
            upd_w1 + (size_t)l * 4096, upd_b1 + l * 64,
            upd_w2 + (size_t)l * 4096, upd_b2 + l * 64,
            ln_g + l * 64, ln_b + l * 64, h_nxt, hb_nxt, N);
        float* tf = h_cur; h_cur = h_nxt; h_nxt = tf;
        ushort_t* tb2 = hb_cur; hb_cur = hb_nxt; hb_nxt = tb2;
    }

    out_kernel<<<((N * 32) + 255) / 256, 256, 0, stream>>>(h_cur, toU_w, toU_b,
                                                           (float*)d_out, N);
}

// Round 10
// 660.998 us; speedup vs baseline: 1.3111x; 1.0706x over previous
//
#include <hip/hip_runtime.h>
#include <math.h>

// ---------------------------------------------------------------------------
// StageA GNN: encoder -> CSR build -> L x (gateproj, gate, agg, upd+LN) -> head
// R10: split the fused agg_update into (a) agg_kernel — pure gather+fma,
// ~45 VGPR -> 8 waves/SIMD, 2x outstanding loads (the latency-bound phase);
// (b) upd_kernel — streaming MLP+LN, coalesced, no gathers. The m/deg
// round-trip (26 MB) is far cheaper than the occupancy win.
// enc keeps R9's LDS staging; everything else unchanged.
// ---------------------------------------------------------------------------

typedef unsigned short ushort_t;

__device__ __forceinline__ float bf2f(ushort_t u) {
    return __uint_as_float(((unsigned int)u) << 16);
}
__device__ __forceinline__ ushort_t f2bf(float f) {
    unsigned int x = __float_as_uint(f);
    unsigned int lsb = (x >> 16) & 1u;
    x += 0x7fffu + lsb;                 // round-to-nearest-even
    return (ushort_t)(x >> 16);
}

__device__ __forceinline__ float wave_sum64(float v) {
    #pragma unroll
    for (int o = 32; o > 0; o >>= 1) v += __shfl_xor(v, o, 64);
    return v;
}

// h = relu(relu(x@W1+b1)@W2+b2).  W1 in LDS (64KB, k-major); x in 16-row
// LDS tiles (16KB, coalesced stage). R9 version (proven).
__global__ __launch_bounds__(256) void enc_kernel(
    const float* __restrict__ x, const float* __restrict__ w1,
    const float* __restrict__ b1, const float* __restrict__ w2,
    const float* __restrict__ b2,
    float* __restrict__ h, ushort_t* __restrict__ hb, int N, int C) {
    __shared__ float ws1[256 * 64];   // 64 KB
    __shared__ float xs[16 * 256];    // 16 KB
    const int tid  = threadIdx.x;
    const int lane = tid & 63;
    const int wvid = tid >> 6;        // 0..3
    const float b1l = b1[lane], b2l = b2[lane];
    for (int i = tid; i < 256 * 64; i += 256) ws1[i] = w1[i];
    const int ntile = (N + 15) >> 4;
    for (int tile = blockIdx.x; tile < ntile; tile += gridDim.x) {
        const int rbase = tile << 4;
        const int rows = min(16, N - rbase);
        __syncthreads();              // previous tile fully consumed
        {   // coalesced stage: rows*64 float4
            const float4* s4 = (const float4*)(x + (size_t)rbase * 256);
            float4* d4 = (float4*)xs;
            for (int i = tid; i < rows * 64; i += 256) d4[i] = s4[i];
        }
        __syncthreads();
        const int r0 = wvid * 4;
        if (r0 + 4 <= rows) {
            const float* xr = xs + r0 * 256;
            float s0 = 0.f, s1 = 0.f, s2 = 0.f, s3 = 0.f;
            #pragma unroll 8
            for (int k4 = 0; k4 < 64; ++k4) {
                const float* wp = ws1 + k4 * 256 + lane;
                float wa = wp[0], wbv = wp[64], wc = wp[128], wd = wp[192];
                float4 v0 = *(const float4*)(xr + k4 * 4);
                float4 v1 = *(const float4*)(xr + 256 + k4 * 4);
                float4 v2 = *(const float4*)(xr + 512 + k4 * 4);
                float4 v3 = *(const float4*)(xr + 768 + k4 * 4);
                s0 = fmaf(wa, v0.x, s0); s0 = fmaf(wbv, v0.y, s0);
                s0 = fmaf(wc, v0.z, s0); s0 = fmaf(wd, v0.w, s0);
                s1 = fmaf(wa, v1.x, s1); s1 = fmaf(wbv, v1.y, s1);
                s1 = fmaf(wc, v1.z, s1); s1 = fmaf(wd, v1.w, s1);
                s2 = fmaf(wa, v2.x, s2); s2 = fmaf(wbv, v2.y, s2);
                s2 = fmaf(wc, v2.z, s2); s2 = fmaf(wd, v2.w, s2);
                s3 = fmaf(wa, v3.x, s3); s3 = fmaf(wbv, v3.y, s3);
                s3 = fmaf(wc, v3.z, s3); s3 = fmaf(wd, v3.w, s3);
            }
            float t0 = fmaxf(s0 + b1l, 0.f), t1 = fmaxf(s1 + b1l, 0.f);
            float t2 = fmaxf(s2 + b1l, 0.f), t3 = fmaxf(s3 + b1l, 0.f);
            float c0 = 0.f, c1 = 0.f, c2 = 0.f, c3 = 0.f;
            #pragma unroll
            for (int k = 0; k < 64; ++k) {
                float wv = w2[(size_t)k * 64 + lane];
                c0 = fmaf(wv, __shfl(t0, k, 64), c0);
                c1 = fmaf(wv, __shfl(t1, k, 64), c1);
                c2 = fmaf(wv, __shfl(t2, k, 64), c2);
                c3 = fmaf(wv, __shfl(t3, k, 64), c3);
            }
            float h0 = fmaxf(c0 + b2l, 0.f), h1 = fmaxf(c1 + b2l, 0.f);
            float h2 = fmaxf(c2 + b2l, 0.f), h3 = fmaxf(c3 + b2l, 0.f);
            const int r = rbase + r0;
            h[(size_t)(r + 0) * 64 + lane] = h0;
            h[(size_t)(r + 1) * 64 + lane] = h1;
            h[(size_t)(r + 2) * 64 + lane] = h2;
            h[(size_t)(r + 3) * 64 + lane] = h3;
            hb[(size_t)(r + 0) * 64 + lane] = f2bf(h0);
            hb[(size_t)(r + 1) * 64 + lane] = f2bf(h1);
            hb[(size_t)(r + 2) * 64 + lane] = f2bf(h2);
            hb[(size_t)(r + 3) * 64 + lane] = f2bf(h3);
        } else {
            for (int rr = r0; rr < min(r0 + 4, rows); ++rr) {
                const float* xr = xs + rr * 256;
                float acc = 0.f;
                #pragma unroll 8
                for (int k4 = 0; k4 < 64; ++k4) {
                    const float* wp = ws1 + k4 * 256 + lane;
                    float4 v = *(const float4*)(xr + k4 * 4);
                    acc = fmaf(wp[0],   v.x, acc);
                    acc = fmaf(wp[64],  v.y, acc);
                    acc = fmaf(wp[128], v.z, acc);
                    acc = fmaf(wp[192], v.w, acc);
                }
                float t = fmaxf(acc + b1l, 0.f);
                float acc2 = 0.f;
                #pragma unroll
                for (int k = 0; k < 64; ++k)
                    acc2 = fmaf(w2[(size_t)k * 64 + lane], __shfl(t, k, 64), acc2);
                float hv = fmaxf(acc2 + b2l, 0.f);
                const int r = rbase + rr;
                h[(size_t)r * 64 + lane] = hv;
                hb[(size_t)r * 64 + lane] = f2bf(hv);
            }
        }
    }
}

// ---- CSR build (once per call, reused by both layers) ----
__global__ __launch_bounds__(256) void hist_kernel(
    const int* __restrict__ dst, int* __restrict__ cnt, int E) {
    for (int e = blockIdx.x * blockDim.x + threadIdx.x; e < E;
         e += gridDim.x * blockDim.x)
        atomicAdd(&cnt[dst[e]], 1);
}

// single-block exclusive scan: cnt[N] -> row_ptr[N+1]
__global__ __launch_bounds__(1024) void scan_kernel(
    const int* __restrict__ cnt, int* __restrict__ row_ptr, int N) {
    __shared__ int sums[1024];
    const int tid = threadIdx.x;
    const int chunk = (N + 1023) / 1024;
    const int beg = tid * chunk;
    const int end = min(beg + chunk, N);
    int s = 0;
    for (int i = beg; i < end; ++i) s += cnt[i];
    sums[tid] = s;
    __syncthreads();
    for (int off = 1; off < 1024; off <<= 1) {
        int v = (tid >= off) ? sums[tid - off] : 0;
        __syncthreads();
        sums[tid] += v;
        __syncthreads();
    }
    int run = (tid == 0) ? 0 : sums[tid - 1];
    for (int i = beg; i < end; ++i) {
        row_ptr[i] = run;
        run += cnt[i];
    }
    if (tid == 1023) row_ptr[N] = sums[1023];
}

// fill dst-grouped records: (src, dst, base_w*sig(rr_s)*sig(rr_d), pad)
__global__ __launch_bounds__(256) void scatter_kernel(
    const int* __restrict__ src, const int* __restrict__ dst,
    const float* __restrict__ base_w, const float* __restrict__ rr,
    const int* __restrict__ row_ptr, int* __restrict__ fill,
    int4* __restrict__ recs, int E) {
    for (int e = blockIdx.x * blockDim.x + threadIdx.x; e < E;
         e += gridDim.x * blockDim.x) {
        int s = src[e], d = dst[e];
        int pos = row_ptr[d] + atomicAdd(&fill[d], 1);
        float rs = 1.f / (1.f + __expf(-rr[s]));
        float rd = 1.f / (1.f + __expf(-rr[d]));
        float c = base_w[e] * rs * rd;
        recs[pos] = make_int4(s, d, __float_as_int(c), 0);
    }
}

// gate projection: ab = bf16(h@gw1[0:64]+gb1), bbuf = h@gw1[64:128]; k-major
__global__ __launch_bounds__(256) void gateproj_kernel(
    const float* __restrict__ h, const float* __restrict__ gw1,
    const float* __restrict__ gb1, ushort_t* __restrict__ ab,
    float* __restrict__ bbuf, int N) {
    const int lane = threadIdx.x & 63;
    const int wid  = blockIdx.x * (blockDim.x >> 6) + (threadIdx.x >> 6);
    const int nw   = gridDim.x * (blockDim.x >> 6);
    const float gbl = gb1[lane];
    for (int r = wid; r < N; r += nw) {
        float hv = h[(size_t)r * 64 + lane];
        float aa = 0.f, bv = 0.f;
        #pragma unroll
        for (int k = 0; k < 64; ++k) {
            float tv = __shfl(hv, k, 64);
            aa = fmaf(gw1[(size_t)k * 64 + lane], tv, aa);
            bv = fmaf(gw1[(size_t)(64 + k) * 64 + lane], tv, bv);
        }
        ab[(size_t)r * 64 + lane] = f2bf(aa + gbl);
        bbuf[(size_t)r * 64 + lane] = bv;
    }
}

// 16 lanes per edge: z = relu(a[s]+bb[d]) dot gw2 (4 elems/lane, 4-step reduce)
// w = c * sigmoid(z + gb2);  sw[e] = (s, w).  a gathered as bf16 (8B/lane).
__global__ __launch_bounds__(256) void gate_kernel(
    const int4* __restrict__ recs, const ushort_t* __restrict__ ab,
    const float* __restrict__ bb, const float* __restrict__ gw2,
    const float* __restrict__ gb2, int2* __restrict__ sw, int E) {
    const int lane = threadIdx.x & 63;
    const int sub  = lane & 15;                       // feature slice id
    const float4 gv = ((const float4*)gw2)[sub];
    const float gb = gb2[0];
    int grp  = (blockIdx.x * blockDim.x + threadIdx.x) >> 4;
    const int ngrp = (gridDim.x * blockDim.x) >> 4;
    for (int e = grp; e < E; e += ngrp) {
        int4 r = recs[e];                             // broadcast within group
        ushort4 av = ((const ushort4*)(ab + (size_t)r.x * 64))[sub];
        float4 bv = ((const float4*)(bb + (size_t)r.y * 64))[sub];
        float t = fmaxf(bf2f(av.x) + bv.x, 0.f) * gv.x
                + fmaxf(bf2f(av.y) + bv.y, 0.f) * gv.y
                + fmaxf(bf2f(av.z) + bv.z, 0.f) * gv.z
                + fmaxf(bf2f(av.w) + bv.w, 0.f) * gv.w;
        #pragma unroll
        for (int o = 8; o > 0; o >>= 1) t += __shfl_xor(t, o, 64);
        float w = __int_as_float(r.z) / (1.f + __expf(-(t + gb)));
        if (sub == 0) sw[e] = make_int2(r.x, __float_as_int(w));
    }
}

// pure gather+fma aggregation (wave-per-node): m[n] = sum w*h_bf16[s],
// deg[n] = sum w. No weights, no cross-lane ops -> low VGPR, 8 waves/SIMD.
__global__ __launch_bounds__(256) void agg_kernel(
    const int* __restrict__ row_ptr, const int2* __restrict__ sw,
    const ushort_t* __restrict__ hb_in,
    float* __restrict__ m, float* __restrict__ deg, int N) {
    const int lane = threadIdx.x & 63;
    const int wid  = blockIdx.x * (blockDim.x >> 6) + (threadIdx.x >> 6);
    const int nw   = gridDim.x * (blockDim.x >> 6);
    for (int n = wid; n < N; n += nw) {
        const int beg = row_ptr[n], end = row_ptr[n + 1];
        float macc = 0.f, dacc = 0.f;
        int i = beg;
        for (; i + 8 <= end; i += 8) {
            int2 r0 = sw[i],     r1 = sw[i + 1], r2 = sw[i + 2], r3 = sw[i + 3];
            int2 r4 = sw[i + 4], r5 = sw[i + 5], r6 = sw[i + 6], r7 = sw[i + 7];
            float hv0 = bf2f(hb_in[(size_t)r0.x * 64 + lane]);
            float hv1 = bf2f(hb_in[(size_t)r1.x * 64 + lane]);
            float hv2 = bf2f(hb_in[(size_t)r2.x * 64 + lane]);
            float hv3 = bf2f(hb_in[(size_t)r3.x * 64 + lane]);
            float hv4 = bf2f(hb_in[(size_t)r4.x * 64 + lane]);
            float hv5 = bf2f(hb_in[(size_t)r5.x * 64 + lane]);
            float hv6 = bf2f(hb_in[(size_t)r6.x * 64 + lane]);
            float hv7 = bf2f(hb_in[(size_t)r7.x * 64 + lane]);
            float w0 = __int_as_float(r0.y), w1v = __int_as_float(r1.y);
            float w2v = __int_as_float(r2.y), w3v = __int_as_float(r3.y);
            float w4v = __int_as_float(r4.y), w5v = __int_as_float(r5.y);
            float w6v = __int_as_float(r6.y), w7v = __int_as_float(r7.y);
            macc = fmaf(w0, hv0, macc);  macc = fmaf(w1v, hv1, macc);
            macc = fmaf(w2v, hv2, macc); macc = fmaf(w3v, hv3, macc);
            macc = fmaf(w4v, hv4, macc); macc = fmaf(w5v, hv5, macc);
            macc = fmaf(w6v, hv6, macc); macc = fmaf(w7v, hv7, macc);
            dacc += ((w0 + w1v) + (w2v + w3v)) + ((w4v + w5v) + (w6v + w7v));
        }
        for (; i < end; ++i) {
            int2 r0 = sw[i];
            float hv0 = bf2f(hb_in[(size_t)r0.x * 64 + lane]);
            float w0 = __int_as_float(r0.y);
            macc = fmaf(w0, hv0, macc);
            dacc += w0;
        }
        m[(size_t)n * 64 + lane] = macc;
        if (lane == 0) deg[n] = dacc;
    }
}

// streaming update MLP + LayerNorm: neigh = m/deg; u = relu(neigh@W1+b1)@W2+b2;
// h_out = LN(h_in + u). k-major weights from global (L1-hot, coalesced).
__global__ __launch_bounds__(256) void upd_kernel(
    const float* __restrict__ m, const float* __restrict__ deg,
    const float* __restrict__ h_in,
    const float* __restrict__ w1, const float* __restrict__ b1,
    const float* __restrict__ w2, const float* __restrict__ b2,
    const float* __restrict__ lng, const float* __restrict__ lnb,
    float* __restrict__ h_out, ushort_t* __restrict__ hb_out, int N) {
    const int lane = threadIdx.x & 63;
    const int wid  = blockIdx.x * (blockDim.x >> 6) + (threadIdx.x >> 6);
    const int nw   = gridDim.x * (blockDim.x >> 6);
    const float b1l = b1[lane], b2l = b2[lane];
    const float gl = lng[lane], bl = lnb[lane];
    for (int n = wid; n < N; n += nw) {
        float neigh = m[(size_t)n * 64 + lane] / (deg[n] + 1e-8f);
        float acc = 0.f;
        #pragma unroll
        for (int k = 0; k < 64; ++k) {
            float tv = __shfl(neigh, k, 64);
            acc = fmaf(w1[(size_t)k * 64 + lane], tv, acc);
        }
        float t = fmaxf(acc + b1l, 0.f);
        float acc2 = 0.f;
        #pragma unroll
        for (int k = 0; k < 64; ++k) {
            float tv = __shfl(t, k, 64);
            acc2 = fmaf(w2[(size_t)k * 64 + lane], tv, acc2);
        }
        float pre = h_in[(size_t)n * 64 + lane] + acc2 + b2l;
        float s1 = wave_sum64(pre);
        float s2 = wave_sum64(pre * pre);
        float mean = s1 * (1.0f / 64.0f);
        float var  = s2 * (1.0f / 64.0f) - mean * mean;
        float hn = (pre - mean) * rsqrtf(var + 1e-5f) * gl + bl;
        h_out[(size_t)n * 64 + lane] = hn;
        hb_out[(size_t)n * 64 + lane] = f2bf(hn);
    }
}

// U = softplus(h @ toU_w + toU_b), K=32
__global__ __launch_bounds__(256) void out_kernel(
    const float* __restrict__ h, const float* __restrict__ tw,
    const float* __restrict__ tb, float* __restrict__ U, int N) {
    int gid = blockIdx.x * blockDim.x + threadIdx.x;
    int n = gid >> 5;
    int k = gid & 31;
    if (n >= N) return;
    float acc = tb[k];
    const float* hr = h + (size_t)n * 64;
    #pragma unroll 8
    for (int j = 0; j < 64; ++j) acc = fmaf(hr[j], tw[j * 32 + k], acc);
    float sp = acc > 0.f ? acc + log1pf(__expf(-acc)) : log1pf(__expf(acc));
    U[(size_t)n * 32 + k] = sp;
}

extern "C" void kernel_launch(void* const* d_in, const int* in_sizes, int n_in,
                              void* d_out, int out_size, void* d_ws, size_t ws_size,
                              hipStream_t stream) {
    const float* x       = (const float*)d_in[0];
    const int*   src     = (const int*)d_in[1];
    const int*   dst     = (const int*)d_in[2];
    const float* base_w  = (const float*)d_in[3];
    const float* enc_w1  = (const float*)d_in[4];
    const float* enc_b1  = (const float*)d_in[5];
    const float* enc_w2  = (const float*)d_in[6];
    const float* enc_b2  = (const float*)d_in[7];
    const float* gate_w1 = (const float*)d_in[8];
    const float* gate_b1 = (const float*)d_in[9];
    const float* gate_w2 = (const float*)d_in[10];
    const float* gate_b2 = (const float*)d_in[11];
    const float* upd_w1  = (const float*)d_in[12];
    const float* upd_b1  = (const float*)d_in[13];
    const float* upd_w2  = (const float*)d_in[14];
    const float* upd_b2  = (const float*)d_in[15];
    const float* ln_g    = (const float*)d_in[16];
    const float* ln_b    = (const float*)d_in[17];
    const float* rho_raw = (const float*)d_in[18];
    const float* toU_w   = (const float*)d_in[19];
    const float* toU_b   = (const float*)d_in[20];

    const int N = in_sizes[18];          // 50000
    const int C = in_sizes[0] / N;       // 256
    const int E = in_sizes[1];           // 800000
    const int L = 2;

    // workspace layout (float units), sections padded to 16B alignment
    float* ws  = (float*)d_ws;
    size_t off = 0;
    float* h0  = ws + off; off += (size_t)N * 64;
    float* h1  = ws + off; off += (size_t)N * 64;
    ushort_t* hb0 = (ushort_t*)(ws + off); off += (size_t)N * 32;
    ushort_t* hb1 = (ushort_t*)(ws + off); off += (size_t)N * 32;
    ushort_t* ab  = (ushort_t*)(ws + off); off += (size_t)N * 32;
    float* bb  = ws + off; off += (size_t)N * 64;
    float* m   = ws + off; off += (size_t)N * 64;
    float* deg = ws + off; off += (size_t)((N + 3) & ~3);
    int* row_ptr = (int*)(ws + off); off += (size_t)((N + 1 + 3) & ~3);
    int* cnt     = (int*)(ws + off); off += (size_t)((N + 3) & ~3);
    int4* recs   = (int4*)(ws + off); off += (size_t)E * 4;   // (s,d,c,0)
    int2* sw     = (int2*)(ws + off); off += (size_t)E * 2;   // (s,w)

    enc_kernel<<<1024, 256, 0, stream>>>(x, enc_w1, enc_b1, enc_w2, enc_b2,
                                         h0, hb0, N, C);

    // CSR build (dst-sorted edge records); rho folded into scatter
    hipMemsetAsync(cnt, 0, (size_t)N * sizeof(int), stream);
    hist_kernel<<<(E + 255) / 256, 256, 0, stream>>>(dst, cnt, E);
    scan_kernel<<<1, 1024, 0, stream>>>(cnt, row_ptr, N);
    hipMemsetAsync(cnt, 0, (size_t)N * sizeof(int), stream);
    scatter_kernel<<<(E + 255) / 256, 256, 0, stream>>>(src, dst, base_w, rho_raw,
                                                        row_ptr, cnt, recs, E);

    float* h_cur = h0;  ushort_t* hb_cur = hb0;
    float* h_nxt = h1;  ushort_t* hb_nxt = hb1;
    for (int l = 0; l < L; ++l) {
        gateproj_kernel<<<1024, 256, 0, stream>>>(h_cur, gate_w1, gate_b1,
                                                  ab, bb, N);
        gate_kernel<<<4096, 256, 0, stream>>>(recs, ab, bb, gate_w2, gate_b2, sw, E);
        agg_kernel<<<2048, 256, 0, stream>>>(row_ptr, sw, hb_cur, m, deg, N);
        upd_kernel<<<1024, 256, 0, stream>>>(
            m, deg, h_cur,
            upd_w1 + (size_t)l * 4096, upd_b1 + l * 64,
            upd_w2 + (size_t)l * 4096, upd_b2 + l * 64,
            ln_g + l * 64, ln_b + l * 64, h_nxt, hb_nxt, N);
        float* tf = h_cur; h_cur = h_nxt; h_nxt = tf;
        ushort_t* tb2 = hb_cur; hb_cur = hb_nxt; hb_nxt = tb2;
    }

    out_kernel<<<((N * 32) + 255) / 256, 256, 0, stream>>>(h_cur, toU_w, toU_b,
                                                           (float*)d_out, N);
}